// Round 19
// baseline (200.216 us; speedup 1.0000x reference)
//
#include <hip/hip_runtime.h>

typedef _Float16 f16;
typedef _Float16 f16x8 __attribute__((ext_vector_type(8)));
typedef float f32x4 __attribute__((ext_vector_type(4)));

#define MFMA16(a, b, c) __builtin_amdgcn_mfma_f32_16x16x32_f16((a), (b), (c), 0, 0, 0)

constexpr int SEQ   = 16;
constexpr int PLEN  = 15;
constexpr int BATCH = 32768;
constexpr int POSE  = 34;
constexpr int HD    = 64;

constexpr float LOG2E   = 1.4426950408889634f;
constexpr float LOG2E2  = 2.8853900817779268f;
constexpr float NLOG2E2 = -2.8853900817779268f;

// d_ws byte layout (prep outputs)
constexpr size_t OFF_ENC  = 0;         // [256][128] f16 enc W' (bias col @98, log2e-scaled)
constexpr size_t OFF_DEC0 = 65536;     // [256][128] f16 dec W' (original, for decoder step 0)
constexpr size_t OFF_EFF  = 131072;    // [256][64]  f16 W_eff = Whh_d + Wih_d@fc_w (scaled)
constexpr size_t OFF_FCW  = 163840;    // [48][64]   f16 fc_w (rows>=34 zero)
constexpr size_t OFF_BEFF = 169984;    // [256]      f32 b_eff = (b_d + Wih_d@fc_b)*sc

__device__ __forceinline__ float rcpf(float x)   { return __builtin_amdgcn_rcpf(x); }
__device__ __forceinline__ float exp2f_(float x) { return __builtin_amdgcn_exp2f(x); }

// ---------- one-time weight prep (R5-validated numerics) ----------
__global__ void prep(const float* __restrict__ Wih_e, const float* __restrict__ Whh_e,
                     const float* __restrict__ b_e,
                     const float* __restrict__ Wih_d, const float* __restrict__ Whh_d,
                     const float* __restrict__ b_d,
                     const float* __restrict__ fc_w, const float* __restrict__ fc_b,
                     f16* wEnc, f16* wDec0, f16* wEff, f16* wFc, float* bEff)
{
    const int r = blockIdx.x * 64 + threadIdx.x;   // gate row 0..255
    const float sc = (r >= 128 && r < 192) ? LOG2E2 : LOG2E;

    #pragma unroll 4
    for (int c = 0; c < 128; ++c) {
        float ve = 0.f, vd = 0.f;
        if (c < 64)       { ve = Whh_e[r * 64 + c];        vd = Whh_d[r * 64 + c]; }
        else if (c < 98)  { ve = Wih_e[r * 34 + (c - 64)]; vd = Wih_d[r * 34 + (c - 64)]; }
        else if (c == 98) { ve = b_e[r];                   vd = b_d[r]; }
        wEnc[r * 128 + c]  = (f16)(ve * sc);
        wDec0[r * 128 + c] = (f16)(vd * sc);
    }
    float wih[POSE];
    #pragma unroll
    for (int p = 0; p < POSE; ++p) wih[p] = Wih_d[r * POSE + p];
    for (int k = 0; k < HD; ++k) {
        float acc = Whh_d[r * HD + k];
        #pragma unroll
        for (int p = 0; p < POSE; ++p) acc += wih[p] * fc_w[p * HD + k];
        wEff[r * HD + k] = (f16)(acc * sc);
    }
    float bb = b_d[r];
    #pragma unroll
    for (int p = 0; p < POSE; ++p) bb += wih[p] * fc_b[p];
    bEff[r] = bb * sc;

    if (r < 48) {
        for (int k = 0; k < HD; ++k)
            wFc[r * HD + k] = (f16)((r < POSE) ? fc_w[r * HD + k] : 0.f);
    }
}

// ---------- main: fully autonomous waves, ZERO barriers ----------
// Each wave: 16 batch rows, all 256 gate cols, weights register-resident
// (Bw[16][4] = 256 VGPR), h via wave-private LDS (lgkmcnt only).
__global__ __launch_bounds__(256, 1)
void lstm19(const float* __restrict__ obs,
            const f16* __restrict__ wEnc, const f16* __restrict__ wDec0,
            const f16* __restrict__ wEff, const f16* __restrict__ wFc,
            const float* __restrict__ bEff, const float* __restrict__ fc_b,
            float* __restrict__ out)
{
    __shared__ f16 hls[4][16][72];   // per-wave private h buffer (72: 16B-aligned rows)

    const int tid  = threadIdx.x;
    const int lane = tid & 63;
    const int w    = tid >> 6;
    const int l15  = lane & 15;
    const int l4   = lane >> 4;
    const int bbase = blockIdx.x * 64 + w * 16;   // this wave's 16 batch rows

    // zero my private h region (h0 = 0); same-wave ordering via lgkmcnt, no barrier
    {
        f16* hw = &hls[w][0][0];
        for (int i = lane; i < 16 * 72; i += 64) hw[i] = (f16)0.f;
    }

    // ---- register-resident weights: all 256 gate cols ----
    f16x8 Bw[16][4];
    auto loadW128 = [&](const f16* __restrict__ W) {
        #pragma unroll
        for (int cf = 0; cf < 16; ++cf)
            #pragma unroll
            for (int kf = 0; kf < 4; ++kf)
                Bw[cf][kf] = *(const f16x8*)&W[(cf * 16 + l15) * 128 + kf * 32 + l4 * 8];
    };
    auto loadW64 = [&](const f16* __restrict__ W) {
        #pragma unroll
        for (int cf = 0; cf < 16; ++cf)
            #pragma unroll
            for (int kf = 0; kf < 2; ++kf)
                Bw[cf][kf] = *(const f16x8*)&W[(cf * 16 + l15) * 64 + kf * 32 + l4 * 8];
    };
    loadW128(wEnc);

    // ---- x prefetch: straight global -> regs (8B-aligned float2 ok: 136 % 8 == 0) ----
    float xp[8];
    float xa, xb;
    auto prefx = [&](int ts) {
        const float* xr = obs + ((size_t)ts * BATCH + bbase + l15) * POSE;
        #pragma unroll
        for (int j2 = 0; j2 < 4; ++j2) {
            float2 v = *(const float2*)&xr[l4 * 8 + j2 * 2];
            xp[j2 * 2] = v.x; xp[j2 * 2 + 1] = v.y;
        }
        if (l4 == 0) { float2 t = *(const float2*)&xr[32]; xa = t.x; xb = t.y; }
        else         { xa = 0.f; xb = 0.f; }
    };

    f32x4 cst[4];   // 16 cells/lane: row = l4*4+r, hcol = cf*16+l15
    #pragma unroll
    for (int cf = 0; cf < 4; ++cf) cst[cf] = (f32x4)0.f;

    auto ldh = [&](f16x8& a0, f16x8& a1) {   // h A-frags: row=l15, k=kf*32+l4*8
        a0 = *(const f16x8*)&hls[w][l15][l4 * 8];
        a1 = *(const f16x8*)&hls[w][l15][32 + l4 * 8];
    };
    // merged-rcp nonlin (R13-validated): quad = acc[cf], acc[4+cf], acc[8+cf], acc[12+cf]
    auto nonlin = [&](f32x4 (&acc)[16]) {
        #pragma unroll
        for (int cf = 0; cf < 4; ++cf) {
            #pragma unroll
            for (int r = 0; r < 4; ++r) {
                float Ei = exp2f_(-acc[cf][r]);
                float Ef = exp2f_(-acc[4 + cf][r]);
                float Eg = exp2f_(-acc[8 + cf][r]);    // e^{-2g} (pre-scaled 2log2e)
                float Eo = exp2f_(-acc[12 + cf][r]);
                float pf_ = 1.f + Ef;
                float P   = (1.f + Ei) * (1.f + Eg);
                float cc  = (cst[cf][r] * P + (1.f - Eg) * pf_) * rcpf(pf_ * P);
                float Ec  = exp2f_(cc * NLOG2E2);
                float h   = (1.f - Ec) * rcpf((1.f + Eo) * (1.f + Ec));
                cst[cf][r] = cc;
                hls[w][l4 * 4 + r][cf * 16 + l15] = (f16)h;
            }
        }
    };

    // ======== encoder: 16 steps, barrier-free ========
    prefx(0);
    #pragma unroll 1
    for (int s = 0; s < SEQ; ++s) {
        f16x8 a[4];
        ldh(a[0], a[1]);
        #pragma unroll
        for (int j = 0; j < 8; ++j) a[2][j] = (f16)xp[j];
        a[3] = (f16x8)(f16)0.f;
        if (l4 == 0) { a[3][0] = (f16)xa; a[3][1] = (f16)xb; a[3][2] = (f16)1.0f; }
        prefx(s + 1 < 15 ? s + 1 : 15);      // next x (holds obs[15] after the loop)

        f32x4 acc[16];
        #pragma unroll
        for (int cf = 0; cf < 16; ++cf) acc[cf] = (f32x4)0.f;
        #pragma unroll
        for (int kf = 0; kf < 4; ++kf)
            #pragma unroll
            for (int cf = 0; cf < 16; ++cf)
                acc[cf] = MFMA16(a[kf], Bw[cf][kf], acc[cf]);
        nonlin(acc);
    }

    // ======== decoder step 0: K=128 with wDec0, x = obs[15] (in prefetch) ========
    loadW128(wDec0);
    {
        f16x8 a[4];
        ldh(a[0], a[1]);
        #pragma unroll
        for (int j = 0; j < 8; ++j) a[2][j] = (f16)xp[j];
        a[3] = (f16x8)(f16)0.f;
        if (l4 == 0) { a[3][0] = (f16)xa; a[3][1] = (f16)xb; a[3][2] = (f16)1.0f; }

        f32x4 acc[16];
        #pragma unroll
        for (int cf = 0; cf < 16; ++cf) acc[cf] = (f32x4)0.f;
        #pragma unroll
        for (int kf = 0; kf < 4; ++kf)
            #pragma unroll
            for (int cf = 0; cf < 16; ++cf)
                acc[cf] = MFMA16(a[kf], Bw[cf][kf], acc[cf]);
        nonlin(acc);
    }

    // ======== fused decoder (R9-validated): K=64, bias via b_eff ========
    loadW64(wEff);
    float be[16];
    #pragma unroll
    for (int cf = 0; cf < 16; ++cf) be[cf] = bEff[cf * 16 + l15];
    f16x8 Bfc[3][2];
    float fcb[3];
    #pragma unroll
    for (int pf = 0; pf < 3; ++pf) {
        #pragma unroll
        for (int kf = 0; kf < 2; ++kf)
            Bfc[pf][kf] = *(const f16x8*)&wFc[(pf * 16 + l15) * 64 + kf * 32 + l4 * 8];
        int p = pf * 16 + l15;
        fcb[pf] = (p < POSE) ? fc_b[p] : 0.f;
    }

    f16x8 ah0, ah1;
    ldh(ah0, ah1);                      // h after decoder step 0
    #pragma unroll 1
    for (int t = 0; t < PLEN; ++t) {
        // out[t] = fc(h_t) from the already-loaded h fragments
        #pragma unroll
        for (int pf = 0; pf < 3; ++pf) {
            f32x4 o = {fcb[pf], fcb[pf], fcb[pf], fcb[pf]};
            o = MFMA16(ah0, Bfc[pf][0], o);
            o = MFMA16(ah1, Bfc[pf][1], o);
            int p = pf * 16 + l15;
            if (p < POSE) {
                float* ob = out + ((size_t)t * BATCH + bbase) * POSE;
                #pragma unroll
                for (int r = 0; r < 4; ++r) ob[(l4 * 4 + r) * POSE + p] = o[r];
            }
        }
        if (t == PLEN - 1) break;

        // next h: gates = W_eff @ h + b_eff  (K=64)
        f32x4 acc[16];
        #pragma unroll
        for (int cf = 0; cf < 16; ++cf)
            acc[cf] = (f32x4){be[cf], be[cf], be[cf], be[cf]};
        #pragma unroll
        for (int cf = 0; cf < 16; ++cf) {
            acc[cf] = MFMA16(ah0, Bw[cf][0], acc[cf]);
            acc[cf] = MFMA16(ah1, Bw[cf][1], acc[cf]);
        }
        nonlin(acc);
        ldh(ah0, ah1);
    }
}

extern "C" void kernel_launch(void* const* d_in, const int* in_sizes, int n_in,
                              void* d_out, int out_size, void* d_ws, size_t ws_size,
                              hipStream_t stream) {
    const float* obs   = (const float*)d_in[0];
    const float* Wih_e = (const float*)d_in[1];
    const float* Whh_e = (const float*)d_in[2];
    const float* b_e   = (const float*)d_in[3];
    const float* Wih_d = (const float*)d_in[4];
    const float* Whh_d = (const float*)d_in[5];
    const float* b_d   = (const float*)d_in[6];
    const float* fc_w  = (const float*)d_in[7];
    const float* fc_b  = (const float*)d_in[8];
    float* out = (float*)d_out;

    char* ws = (char*)d_ws;
    f16*   wEnc  = (f16*)(ws + OFF_ENC);
    f16*   wDec0 = (f16*)(ws + OFF_DEC0);
    f16*   wEff  = (f16*)(ws + OFF_EFF);
    f16*   wFc   = (f16*)(ws + OFF_FCW);
    float* bEff  = (float*)(ws + OFF_BEFF);

    prep<<<dim3(4), dim3(64), 0, stream>>>(Wih_e, Whh_e, b_e, Wih_d, Whh_d, b_d,
                                           fc_w, fc_b, wEnc, wDec0, wEff, wFc, bEff);
    lstm19<<<dim3(BATCH / 64), dim3(256), 0, stream>>>(
        obs, wEnc, wDec0, wEff, wFc, bEff, fc_b, out);
}

// Round 20
// 120.501 us; speedup vs baseline: 1.6615x; 1.6615x over previous
//
#include <hip/hip_runtime.h>

typedef _Float16 f16;
typedef __fp16 fp16x2 __attribute__((ext_vector_type(2)));   // native cvt_pkrtz result type
typedef _Float16 f16x8 __attribute__((ext_vector_type(8)));
typedef float f32x4 __attribute__((ext_vector_type(4)));

#define MFMA16(a, b, c) __builtin_amdgcn_mfma_f32_16x16x32_f16((a), (b), (c), 0, 0, 0)

constexpr int SEQ   = 16;
constexpr int PLEN  = 15;
constexpr int BATCH = 32768;
constexpr int POSE  = 34;
constexpr int HD    = 64;
constexpr int GRPS  = 2;     // two independent 32-row chains per wave (champion structure)
constexpr int ROWS  = 32;
constexpr int BROWS = GRPS * ROWS;  // 64 rows per block -> grid 512
constexpr int XROW  = 136;   // [h 0..63 | x 64..97 | 1.0 @98 | 0..127 | pad]

constexpr float LOG2E   = 1.4426950408889634f;
constexpr float LOG2E2  = 2.8853900817779268f;
constexpr float NLOG2E2 = -2.8853900817779268f;

__device__ __forceinline__ float rcpf(float x)   { return __builtin_amdgcn_rcpf(x); }
__device__ __forceinline__ float exp2f_(float x) { return __builtin_amdgcn_exp2f(x); }

// FINAL (R17 champion, restored after R19's barrier-free experiment regressed).
// Structure: 2 waves/EU x 2 independent 32-row chains/wave; register-resident
// gate-sliced weights (q-split); merged-rcp nonlin (7 trans/elem); vectorized
// x-staging; setprio around MFMA bursts; decoder out-stores drained post-barrier.
// Plateau: ~64us conserved VALU issue at ~45% achievable saturation — bounded by
// the register-forced parallelism ceiling of the 31-step serial recurrence.
__global__ __launch_bounds__(256, 2)
void lstm17(const float* __restrict__ obs,
            const float* __restrict__ Wih_e, const float* __restrict__ Whh_e,
            const float* __restrict__ b_e,
            const float* __restrict__ Wih_d, const float* __restrict__ Whh_d,
            const float* __restrict__ b_d,
            const float* __restrict__ fc_w, const float* __restrict__ fc_b,
            float* __restrict__ out)
{
    // [dbuf][grp][row][XROW] activation rows — 34816 B
    __shared__ f16 bfr[2 * GRPS * ROWS * XROW];

    const int tid  = threadIdx.x;
    const int lane = tid & 63;
    const int q    = tid >> 6;     // gate-column split (j = q*16 + l15)
    const int l15  = lane & 15;
    const int l4   = lane >> 4;
    const int blkbase = blockIdx.x * BROWS;

    f16x8 Bw[4][4];
    auto loadB = [&](const float* __restrict__ Wih, const float* __restrict__ Whh,
                     const float* __restrict__ b) {
        #pragma unroll
        for (int gg = 0; gg < 4; ++gg) {
            const int r = (gg * 4 + q) * 16 + l15;
            const float sc = (gg == 2) ? LOG2E2 : LOG2E;
            #pragma unroll
            for (int kf = 0; kf < 2; ++kf) {
                const float* src = Whh + r * HD + kf * 32 + l4 * 8;
                #pragma unroll
                for (int j = 0; j < 8; ++j) Bw[gg][kf][j] = (f16)(src[j] * sc);
            }
            {
                const float* src = Wih + r * POSE + l4 * 8;
                #pragma unroll
                for (int j = 0; j < 8; ++j) Bw[gg][2][j] = (f16)(src[j] * sc);
            }
            #pragma unroll
            for (int j = 0; j < 8; ++j) {
                const int k = 96 + l4 * 8 + j;
                float v = 0.f;
                if (k < 98)       v = Wih[r * POSE + (k - 64)];
                else if (k == 98) v = b[r];
                Bw[gg][3][j] = (f16)(v * sc);
            }
        }
    };
    loadB(Wih_e, Whh_e, b_e);

    // pairwise-vectorized x staging: float2 -> cvt_pkrtz -> b32 LDS store
    auto stage_x = [&](int ts, int dstbuf) {
        const float* src = obs + ((size_t)ts * BATCH + blkbase) * POSE;
        #pragma unroll
        for (int it = 0; it < 5; ++it) {
            int ip = it * 256 + tid;            // pair index
            if (ip < BROWS * POSE / 2) {
                int i = ip * 2;
                int row = i / POSE, col = i - row * POSE;   // col even
                float2 v = *(const float2*)&src[i];
                fp16x2 h2 = __builtin_amdgcn_cvt_pkrtz(v.x, v.y);
                *(fp16x2*)&bfr[((dstbuf * GRPS + (row >> 5)) * ROWS + (row & 31)) * XROW + HD + col] = h2;
            }
        }
    };

    // fc weights / bias, register-resident
    const int  p    = q * 16 + l15;
    const bool fcok = (q < 3);
    f16x8 Bfc[2];
    #pragma unroll
    for (int kf = 0; kf < 2; ++kf)
        #pragma unroll
        for (int j = 0; j < 8; ++j)
            Bfc[kf][j] = (f16)((fcok && p < POSE) ? fc_w[p * HD + kf * 32 + l4 * 8 + j] : 0.f);
    const float fcb = (fcok && p < POSE) ? fc_b[p] : 0.f;

    // init: h0 = 0, bias col = 1.0
    for (int i = tid; i < 2 * GRPS * ROWS * XROW; i += 256) {
        int c = i % XROW;
        bfr[i] = (c == 98) ? (f16)1.0f : (f16)0.0f;
    }
    __syncthreads();
    stage_x(0, 0);
    __syncthreads();

    f32x4 cst[GRPS][2];
    #pragma unroll
    for (int g = 0; g < GRPS; ++g) { cst[g][0] = (f32x4)0.f; cst[g][1] = (f32x4)0.f; }

    auto ldA = [&](int grp, int srcbuf, f16x8 (&a)[2][4]) {
        #pragma unroll
        for (int mf = 0; mf < 2; ++mf)
            #pragma unroll
            for (int kf = 0; kf < 4; ++kf)
                a[mf][kf] = *(const f16x8*)&bfr[((srcbuf * GRPS + grp) * ROWS + mf * 16 + l15) * XROW + kf * 32 + l4 * 8];
    };
    auto gates = [&](const f16x8 (&a)[2][4], f32x4 (&acc)[2][4]) {
        #pragma unroll
        for (int mf = 0; mf < 2; ++mf)
            #pragma unroll
            for (int gg = 0; gg < 4; ++gg) acc[mf][gg] = (f32x4)0.f;
        #pragma unroll
        for (int kf = 0; kf < 4; ++kf)
            #pragma unroll
            for (int gg = 0; gg < 4; ++gg) {
                acc[0][gg] = MFMA16(a[0][kf], Bw[gg][kf], acc[0][gg]);
                acc[1][gg] = MFMA16(a[1][kf], Bw[gg][kf], acc[1][gg]);
            }
    };
    // merged-rcp nonlin: 5 exp2 + 2 rcp per element
    auto nonlin = [&](int grp, f32x4 (&acc)[2][4], int dstbuf) {
        #pragma unroll
        for (int mf = 0; mf < 2; ++mf) {
            #pragma unroll
            for (int r = 0; r < 4; ++r) {
                float Ei = exp2f_(-acc[mf][0][r]);
                float Ef = exp2f_(-acc[mf][1][r]);
                float Eg = exp2f_(-acc[mf][2][r]);   // e^{-2g} (pre-scaled 2log2e)
                float Eo = exp2f_(-acc[mf][3][r]);
                float pf = 1.f + Ef;
                float P  = (1.f + Ei) * (1.f + Eg);
                float cc = (cst[grp][mf][r] * P + (1.f - Eg) * pf) * rcpf(pf * P);
                float Ec = exp2f_(cc * NLOG2E2);
                float h  = (1.f - Ec) * rcpf((1.f + Eo) * (1.f + Ec));
                cst[grp][mf][r] = cc;
                bfr[((dstbuf * GRPS + grp) * ROWS + mf * 16 + l4 * 4 + r) * XROW + q * 16 + l15] = (f16)h;
            }
        }
    };
    // fc compute + LDS feedback only (pre-barrier); o kept in registers
    auto fc_calc = [&](int grp, int srcbuf, f32x4& o0, f32x4& o1) {
        if (!fcok) return;
        f16x8 ah[2][2];
        #pragma unroll
        for (int mf = 0; mf < 2; ++mf)
            #pragma unroll
            for (int kf = 0; kf < 2; ++kf)
                ah[mf][kf] = *(const f16x8*)&bfr[((srcbuf * GRPS + grp) * ROWS + mf * 16 + l15) * XROW + kf * 32 + l4 * 8];
        o0 = (f32x4){fcb, fcb, fcb, fcb};
        o1 = (f32x4){fcb, fcb, fcb, fcb};
        #pragma unroll
        for (int kf = 0; kf < 2; ++kf) {
            o0 = MFMA16(ah[0][kf], Bfc[kf], o0);
            o1 = MFMA16(ah[1][kf], Bfc[kf], o1);
        }
        if (p < POSE) {
            #pragma unroll
            for (int r = 0; r < 4; ++r) {
                int r0 = l4 * 4 + r, r1 = 16 + l4 * 4 + r;
                bfr[((srcbuf * GRPS + grp) * ROWS + r0) * XROW + HD + p] = (f16)o0[r];  // feedback
                bfr[((srcbuf * GRPS + grp) * ROWS + r1) * XROW + HD + p] = (f16)o1[r];
            }
        }
    };
    // global stores issued post-barrier; drain hidden under next step's gates+nonlin
    auto store_out = [&](int grp, int t, const f32x4& o0, const f32x4& o1) {
        if (!fcok || p >= POSE) return;
        float* ob = out + ((size_t)t * BATCH + blkbase + grp * ROWS) * POSE;
        #pragma unroll
        for (int r = 0; r < 4; ++r) {
            ob[(l4 * 4 + r) * POSE + p]      = o0[r];
            ob[(16 + l4 * 4 + r) * POSE + p] = o1[r];
        }
    };

    int cur = 0;

    // ======== encoder: 16 steps, 1 barrier/step ========
    #pragma unroll 1
    for (int s = 0; s < SEQ; ++s) {
        const int nxt = cur ^ 1;
        f16x8 aA[2][4], aB[2][4];
        f32x4 accA[2][4], accB[2][4];
        __builtin_amdgcn_s_setprio(1);          // favor this wave through the MFMA burst
        ldA(0, cur, aA);
        gates(aA, accA);
        ldA(1, cur, aB);
        gates(aB, accB);
        __builtin_amdgcn_s_setprio(0);
        { int ts = s + 1 < 15 ? s + 1 : 15; stage_x(ts, nxt); }
        nonlin(0, accA, nxt);
        nonlin(1, accB, nxt);
        __syncthreads();
        cur = nxt;
    }

    // ======== decoder: 15 steps, two barriers, stores post-barrier ========
    loadB(Wih_d, Whh_d, b_d);
    #pragma unroll 1
    for (int t = 0; t < PLEN; ++t) {
        const int nxt = cur ^ 1;
        f16x8 aA[2][4], aB[2][4];
        f32x4 accA[2][4], accB[2][4];
        __builtin_amdgcn_s_setprio(1);
        ldA(0, cur, aA);
        gates(aA, accA);
        ldA(1, cur, aB);
        gates(aB, accB);
        __builtin_amdgcn_s_setprio(0);
        nonlin(0, accA, nxt);
        nonlin(1, accB, nxt);
        __syncthreads();              // h complete -> fc reads full 64-wide h
        f32x4 oA0, oA1, oB0, oB1;
        fc_calc(0, nxt, oA0, oA1);    // MFMA + LDS feedback (no global traffic)
        fc_calc(1, nxt, oB0, oB1);
        __syncthreads();              // feedback visible before next step's A-reads
        store_out(0, t, oA0, oA1);    // stores drain at NEXT step's barrier — hidden
        store_out(1, t, oB0, oB1);
        cur = nxt;
    }
}

extern "C" void kernel_launch(void* const* d_in, const int* in_sizes, int n_in,
                              void* d_out, int out_size, void* d_ws, size_t ws_size,
                              hipStream_t stream) {
    const float* obs   = (const float*)d_in[0];
    const float* Wih_e = (const float*)d_in[1];
    const float* Whh_e = (const float*)d_in[2];
    const float* b_e   = (const float*)d_in[3];
    const float* Wih_d = (const float*)d_in[4];
    const float* Whh_d = (const float*)d_in[5];
    const float* b_d   = (const float*)d_in[6];
    const float* fc_w  = (const float*)d_in[7];
    const float* fc_b  = (const float*)d_in[8];
    float* out = (float*)d_out;

    lstm17<<<dim3(BATCH / BROWS), dim3(256), 0, stream>>>(
        obs, Wih_e, Whh_e, b_e, Wih_d, Whh_d, b_d, fc_w, fc_b, out);
}